// Round 1
// baseline (124.449 us; speedup 1.0000x reference)
//
#include <hip/hip_runtime.h>
#include <math.h>

// CircleLoss fused — R9: negatives-only main loop + per-class positive
// correction (exploits label sparsity: ~16 positives per row of 8192).
// Main tile loop computes only e_n = 2^(u^2), u = max(fma(s,CE1,CE0),0)
// (6 VALU/elem vs ~18 for the old dual-path + target-compare epilogue).
// Diagonal excluded via cndmask on diag tiles only. Positives (and the
// e_n over-count for same-class pairs) fixed by a tiny per-class pass at
// the head of each simloss block (block == class), using buckets built in
// the normalize kernel. Pipeline/barrier structure unchanged from R8:
// upper-tri 128x128 tiles, pair scheduling, A in regs, B LDS-dbuf staged
// by stage waves, fence-free counter finalize.

#define NR    8192
#define DIMK  128
#define NT    64
#define NBLKS 512
#define NCLS  512
#define MAXC  120

// e_n(s) = exp(64*max(s-0.25,0)^2) = 2^(u*u), u = max(fma(s,CE1,CE0),0)
// CE1 = 8*sqrt(log2(e)), CE0 = -0.25*CE1
#define CE1 9.6089795f
#define CE0 -2.4022449f

typedef __attribute__((ext_vector_type(8))) short short8;
typedef __attribute__((ext_vector_type(4))) float f32x4;
typedef __attribute__((address_space(3))) uint32_t lds_u32;
typedef const __attribute__((address_space(1))) uint32_t glb_u32;

__device__ __forceinline__ unsigned short bf16_rne(float f) {
  uint32_t u = __float_as_uint(f);
  u += 0x7FFFu + ((u >> 16) & 1u);
  return (unsigned short)(u >> 16);
}

__device__ __forceinline__ float fexp2(float x) {
#if __has_builtin(__builtin_amdgcn_exp2f)
  return __builtin_amdgcn_exp2f(x);
#else
  return exp2f(x);
#endif
}

// ws: xhi bf16[NR*DIMK] | xlo | gP f32[NR] | gN f32[NR] | cnt[NCLS] | idx[NCLS*MAXC] | counter

__global__ __launch_bounds__(256) void normalize_split_kernel(
    const float* __restrict__ x, const int* __restrict__ tgt,
    unsigned short* __restrict__ xhi, unsigned short* __restrict__ xlo,
    float* __restrict__ gP, float* __restrict__ gN,
    int* __restrict__ cnt, int* __restrict__ idx, int* __restrict__ counter) {
  if (blockIdx.x < 32)      gP[blockIdx.x * 256 + threadIdx.x] = 0.f;
  else if (blockIdx.x < 64) gN[(blockIdx.x - 32) * 256 + threadIdx.x] = 0.f;
  if (blockIdx.x == 64 && threadIdx.x == 0) *counter = 0;

  const int wave = threadIdx.x >> 6;
  const int lane = threadIdx.x & 63;
  const int row  = blockIdx.x * 4 + wave;

  // bucket row by label (cnt pre-zeroed by memset node)
  if (lane == 0) {
    const int t = tgt[row];
    const int slot = atomicAdd(&cnt[t], 1);
    if (slot < MAXC) idx[t * MAXC + slot] = row;
  }

  const float2 v = ((const float2*)(x + (size_t)row * DIMK))[lane];
  float ss = v.x * v.x + v.y * v.y;
  #pragma unroll
  for (int s = 1; s < 64; s <<= 1) ss += __shfl_xor(ss, s);
  const float r = rsqrtf(ss);
  const float a = v.x * r, b = v.y * r;
  const unsigned short ha = bf16_rne(a), hb = bf16_rne(b);
  const float haf = __uint_as_float((uint32_t)ha << 16);
  const float hbf = __uint_as_float((uint32_t)hb << 16);
  ushort2 hi, lo;
  hi.x = ha; hi.y = hb;
  lo.x = bf16_rne(a - haf); lo.y = bf16_rne(b - hbf);
  ((ushort2*)xhi)[(size_t)row * 64 + lane] = hi;
  ((ushort2*)xlo)[(size_t)row * 64 + lane] = lo;
}

__global__ __launch_bounds__(512, 2) void simloss_kernel(
    const unsigned short* __restrict__ xhi, const unsigned short* __restrict__ xlo,
    const int* __restrict__ cnt, const int* __restrict__ idx,
    float* __restrict__ gP, float* __restrict__ gN,
    int* __restrict__ counter, float* __restrict__ out) {
  __shared__ unsigned short S[32768];   // 64KB: corr scratch, A stage, B dbuf
  __shared__ float colbuf[2][4][128];   // 4KB, double-buffered col partials (N only)
  __shared__ float red[512];
  __shared__ int midx[MAXC];
  __shared__ int islast;

  const int tid  = threadIdx.x;
  const int wave = tid >> 6, lane = tid & 63;
  const int wy = wave & 3, wx = wave >> 2;   // frag grid: 4 row-waves x 2 col-waves
  const int q = lane >> 4, mcol = lane & 15;
  const bool isStage = (wy == 1) || (wy == 2);
  const bool isFlush = (wy == 0);
  const int srank = (wy - 1) + wx * 2;       // 0..3 for stage waves

  // ---- per-class positive correction (block == class), before S is reused ----
  {
    float* Sf = (float*)S;                   // stride-129 f32 rows (bank-safe)
    const int cn = cnt[blockIdx.x];
    const int m  = (cn < MAXC) ? cn : MAXC;
    if (tid < m) midx[tid] = idx[blockIdx.x * MAXC + tid];
    __syncthreads();
    for (int v = tid; v < m * 128; v += 512) {
      const int r = v >> 7, d = v & 127;
      const int row = midx[r];
      const float hi = __uint_as_float((uint32_t)xhi[(size_t)row * DIMK + d] << 16);
      const float lo = __uint_as_float((uint32_t)xlo[(size_t)row * DIMK + d] << 16);
      Sf[r * 129 + d] = hi + lo;
    }
    __syncthreads();
    for (int pr = tid; pr < m * m; pr += 512) {
      const int i = pr / m, j = pr - i * m;
      const float* vi = &Sf[i * 129];
      const float* vj = &Sf[j * 129];
      float s = 0.f;
      #pragma unroll 8
      for (int d = 0; d < 128; ++d) s = fmaf(vi[d], vj[d], s);
      const int gi = midx[i];
      // positive term: exp(64*max(1.25-s,0)*(s-0.75)); ap==0 -> exp(0)=1 (matches ref)
      const float ep = __expf(fmaxf(1.25f - s, 0.f) * fmaf(s, 64.f, -48.f));
      atomicAdd(&gP[gi], ep);
      if (i != j) {   // remove the e_n the main loop adds for same-class pairs
        const float u = fmaxf(fmaf(s, CE1, CE0), 0.f);
        atomicAdd(&gN[gi], -fexp2(u * u));
      }
    }
    __syncthreads();   // S free for A staging
  }

  const int p  = blockIdx.x >> 4;            // pair index (0..31)
  const int b  = blockIdx.x & 15;
  const int n1 = NT - p;                     // tiles in panel1 (bi=p)
  const int t0 = (b * (NT + 1)) >> 4;        // 65 tiles per pair
  const int t1 = ((b + 1) * (NT + 1)) >> 4;
  const int ntile = t1 - t0;
  const int p2 = NT - 1 - p;                 // panel2 bi

  int cur_bi = (t0 < n1) ? p : p2;

  // ---- A staging (all waves). hi -> S[0..16K), lo -> S[16K..32K) ushorts ----
  auto stageA = [&](int bi) {
    const unsigned short* gh = xhi + (size_t)bi * 128 * DIMK;
    const unsigned short* gl = xlo + (size_t)bi * 128 * DIMK;
    #pragma unroll
    for (int g = 0; g < 4; ++g) {
      const int r  = wave * 16 + g * 4 + (lane >> 4);
      const int sc = (lane & 15) ^ (r & 15);   // XOR swizzle (R6-proven)
      __builtin_amdgcn_global_load_lds((glb_u32*)(gh + (size_t)r * DIMK + sc * 8),
          (lds_u32*)&S[(wave * 16 + g * 4) * 128], 16, 0, 0);
      __builtin_amdgcn_global_load_lds((glb_u32*)(gl + (size_t)r * DIMK + sc * 8),
          (lds_u32*)&S[16384 + (wave * 16 + g * 4) * 128], 16, 0, 0);
    }
  };
  // ---- B staging (stage waves only), 8 instrs each, 32KB tile ----
  auto stageB = [&](int bj, int buf) {
    const unsigned short* gb = xhi + (size_t)bj * 128 * DIMK;
    unsigned short* dst = &S[buf * 16384];
    #pragma unroll
    for (int g = 0; g < 8; ++g) {
      const int r  = srank * 32 + g * 4 + (lane >> 4);
      const int sc = (lane & 15) ^ (r & 15);
      __builtin_amdgcn_global_load_lds((glb_u32*)(gb + (size_t)r * DIMK + sc * 8),
          (lds_u32*)&dst[(srank * 32 + g * 4) * 128], 16, 0, 0);
    }
  };

  short8 Ah[2][4], Al[2][4];
  auto extractA = [&]() {
    #pragma unroll
    for (int fr = 0; fr < 2; ++fr) {
      const int r = wy * 32 + fr * 16 + mcol;
      #pragma unroll
      for (int ks = 0; ks < 4; ++ks) {
        const int pc = (ks * 4 + q) ^ mcol;
        Ah[fr][ks] = *(const short8*)&S[r * 128 + pc * 8];
        Al[fr][ks] = *(const short8*)&S[16384 + r * 128 + pc * 8];
      }
    }
  };

  float rowN[2][4] = {{0.f}};
  auto flushRows = [&](int bi_) {
    #pragma unroll
    for (int fr = 0; fr < 2; ++fr)
      #pragma unroll
      for (int rg = 0; rg < 4; ++rg) {
        float vn = rowN[fr][rg];
        #pragma unroll
        for (int m2 = 1; m2 < 16; m2 <<= 1) vn += __shfl_xor(vn, m2);
        if (mcol == 0)
          atomicAdd(&gN[bi_ * 128 + wy * 32 + fr * 16 + q * 4 + rg], vn);
      }
  };

  stageA(cur_bi);
  __syncthreads();            // A staged
  extractA();
  __builtin_amdgcn_s_waitcnt(49279);   // lgkm0: all frag reads done
  __builtin_amdgcn_s_barrier();        // -> S reusable as B buffers
  if (isStage) stageB((t0 < n1) ? p + t0 : p2 + (t0 - n1), 0);

  for (int tl = 0; tl < ntile; ++tl) {
    const int ix = t0 + tl;
    const int bi = (ix < n1) ? p : p2;
    const int bj = (ix < n1) ? p + ix : p2 + (ix - n1);

    if (bi != cur_bi) {       // panel switch (at most once per block)
      flushRows(cur_bi);
      cur_bi = bi;
      stageA(cur_bi);         // overwrites both B buffers (none pending)
      __syncthreads();
      extractA();
      #pragma unroll
      for (int fr = 0; fr < 2; ++fr)
        #pragma unroll
        for (int rg = 0; rg < 4; ++rg) rowN[fr][rg] = 0.f;
      __builtin_amdgcn_s_waitcnt(49279);
      __builtin_amdgcn_s_barrier();
      if (isStage) stageB(bj, tl & 1);
    }

    // start barrier: only stage waves drain their B loads (vm0+lgkm0 = 112)
    if (isStage) __builtin_amdgcn_s_waitcnt(112);
    __builtin_amdgcn_s_barrier();

    // prefetch next tile's B (same panel only; cross-panel handled above)
    if (tl + 1 < ntile) {
      const int ix2 = ix + 1;
      if ((ix2 < n1) == (ix < n1)) {
        const int bj2 = (ix2 < n1) ? p + ix2 : p2 + (ix2 - n1);
        if (isStage) stageB(bj2, (tl + 1) & 1);
      }
    }

    // ---- compute tile ----
    const unsigned short* Bb = &S[(tl & 1) * 16384];
    f32x4 acc[2][4];
    #pragma unroll
    for (int fr = 0; fr < 2; ++fr)
      #pragma unroll
      for (int fc = 0; fc < 4; ++fc)
        acc[fr][fc] = (f32x4){0.f, 0.f, 0.f, 0.f};
    #pragma unroll
    for (int ks = 0; ks < 4; ++ks) {
      short8 bh[4];
      #pragma unroll
      for (int fc = 0; fc < 4; ++fc) {
        const int rb = wx * 64 + fc * 16 + mcol;
        const int pc = (ks * 4 + q) ^ mcol;
        bh[fc] = *(const short8*)&Bb[rb * 128 + pc * 8];
      }
      #pragma unroll
      for (int fc = 0; fc < 4; ++fc) {
        acc[0][fc] = __builtin_amdgcn_mfma_f32_16x16x32_bf16(Ah[0][ks], bh[fc], acc[0][fc], 0, 0, 0);
        acc[1][fc] = __builtin_amdgcn_mfma_f32_16x16x32_bf16(Ah[1][ks], bh[fc], acc[1][fc], 0, 0, 0);
        acc[0][fc] = __builtin_amdgcn_mfma_f32_16x16x32_bf16(Al[0][ks], bh[fc], acc[0][fc], 0, 0, 0);
        acc[1][fc] = __builtin_amdgcn_mfma_f32_16x16x32_bf16(Al[1][ks], bh[fc], acc[1][fc], 0, 0, 0);
      }
    }

    // ---- epilogue: negatives-only. C layout col = mcol, row = q*4 + rg ----
    float cN[4] = {0.f, 0.f, 0.f, 0.f};
#define EPILOGUE(DIAG_)                                                      \
    {                                                                        \
      _Pragma("unroll")                                                      \
      for (int fr = 0; fr < 2; ++fr) {                                       \
        _Pragma("unroll")                                                    \
        for (int rg = 0; rg < 4; ++rg) {                                     \
          float vn = 0.f;                                                    \
          _Pragma("unroll")                                                  \
          for (int fc = 0; fc < 4; ++fc) {                                   \
            const float s = acc[fr][fc][rg];                                 \
            const float u = fmaxf(fmaf(s, CE1, CE0), 0.f);                   \
            float e = fexp2(u * u);                                          \
            if (DIAG_) {                                                     \
              const int rl = wy * 32 + fr * 16 + q * 4 + rg;                 \
              const int cl = wx * 64 + fc * 16 + mcol;                       \
              e = (rl == cl) ? 0.f : e;                                      \
            }                                                                \
            vn += e;                                                         \
            cN[fc] += e;                                                     \
          }                                                                  \
          rowN[fr][rg] += vn;                                                \
        }                                                                    \
      }                                                                      \
    }
    if (bj == bi) EPILOGUE(true) else EPILOGUE(false)
#undef EPILOGUE

    // col partials: q-reduce then ds_write (16 lanes per wave)
    #pragma unroll
    for (int fc = 0; fc < 4; ++fc) {
      cN[fc] += __shfl_xor(cN[fc], 16);
      cN[fc] += __shfl_xor(cN[fc], 32);
    }
    if (q == 0) {
      #pragma unroll
      for (int fc = 0; fc < 4; ++fc)
        colbuf[tl & 1][wy][wx * 64 + fc * 16 + mcol] = cN[fc];
    }
    __builtin_amdgcn_s_waitcnt(49279);   // lgkm0: colbuf writes visible
    __builtin_amdgcn_s_barrier();

    // flush waves: combine 4 wy slices, fire-and-forget device atomics
    if (isFlush && bj != bi) {
      const int col = wx * 64 + lane;
      float sn = 0.f;
      #pragma unroll
      for (int w = 0; w < 4; ++w) sn += colbuf[tl & 1][w][col];
      atomicAdd(&gN[bj * 128 + col], sn);
    }
  }
  flushRows(cur_bi);

  // ---- fence-free last-block finalize (R4-proven) ----
  __builtin_amdgcn_s_waitcnt(0);   // all my atomics ack'd before counter bump
  __syncthreads();
  if (tid == 0) islast = (atomicAdd(counter, 1) == NBLKS - 1) ? 1 : 0;
  __syncthreads();
  if (islast) {
    float local = 0.f;
    #pragma unroll 1
    for (int bb = 0; bb < 2; ++bb) {
      const int base = bb * 4096 + tid * 8;
      float pv[8], nv[8];
      #pragma unroll
      for (int u = 0; u < 8; ++u) pv[u] = atomicAdd(&gP[base + u], 0.0f);
      #pragma unroll
      for (int u = 0; u < 8; ++u) nv[u] = atomicAdd(&gN[base + u], 0.0f);
      #pragma unroll
      for (int u = 0; u < 8; ++u) local += log1pf(pv[u] * nv[u]);
    }
    red[tid] = local;
    __syncthreads();
    for (int s2 = 256; s2 > 0; s2 >>= 1) {
      if (tid < s2) red[tid] += red[tid + s2];
      __syncthreads();
    }
    if (tid == 0) out[0] = red[0] / (float)NR;
  }
}

extern "C" void kernel_launch(void* const* d_in, const int* in_sizes, int n_in,
                              void* d_out, int out_size, void* d_ws, size_t ws_size,
                              hipStream_t stream) {
  const float* x  = (const float*)d_in[0];
  const int* tgt  = (const int*)d_in[1];
  float* out      = (float*)d_out;

  unsigned short* xhi = (unsigned short*)d_ws;
  unsigned short* xlo = xhi + (size_t)NR * DIMK;
  float* gP = (float*)((char*)d_ws + (size_t)NR * DIMK * 4);
  float* gN = gP + NR;
  int* cnt = (int*)(gN + NR);
  int* idx = cnt + NCLS;
  int* counter = idx + NCLS * MAXC;

  hipMemsetAsync(cnt, 0, NCLS * sizeof(int), stream);
  normalize_split_kernel<<<NR / 4, 256, 0, stream>>>(x, tgt, xhi, xlo, gP, gN, cnt, idx, counter);
  simloss_kernel<<<NBLKS, 512, 0, stream>>>(xhi, xlo, cnt, idx, gP, gN, counter, out);
}